// Round 8
// baseline (848.514 us; speedup 1.0000x reference)
//
#include <hip/hip_runtime.h>
#include <hip/hip_bf16.h>

typedef __hip_bfloat16 bf16;

#define NC_ 100000
#define EC_ 1600000
#define NS_ 50000
#define ES_ 800000
#define G_  1024
#define EPS_ 1e-5f

#define NB_C 782          // ceil(100000/128)
#define NB_S 391          // ceil(50000/128)
#define NBMAX 782
#define KSL 16            // LDS slots per bucket in k_bin

#define WS_REQUIRED 39748612ull

__device__ __forceinline__ float b2f(bf16 v) { return __bfloat162float(v); }

__global__ void DualGNN_31327491457689_kernel() {}

__global__ __launch_bounds__(256) void k_fillout(float* out, float val, int n) {
    int i = blockIdx.x * 256 + threadIdx.x;
    if (i < n) out[i] = val;
}

__global__ __launch_bounds__(256) void k_zero(int* p, int n) {
    int i = blockIdx.x * 256 + threadIdx.x;
    int stride = gridDim.x * 256;
    while (i < n) { p[i] = 0; i += stride; }
}

// ---- Phase A: bucket histogram (LDS-staged) ----------------------------
__global__ __launch_bounds__(256) void k_bhist(const int* dst, int* bcnt, int E, int NB) {
    __shared__ int h[NBMAX];
    int t = threadIdx.x;
    for (int i = t; i < NB; i += 256) h[i] = 0;
    __syncthreads();
    for (int e = blockIdx.x * 256 + t; e < E; e += gridDim.x * 256)
        atomicAdd(&h[dst[e] >> 7], 1);
    __syncthreads();
    for (int i = t; i < NB; i += 256) {
        int v = h[i];
        if (v) atomicAdd(&bcnt[i], v);
    }
}

// ---- Phase B: scan bucket counts (both branches, one block) ------------
__device__ void scan_one(const int* cnt, int* base, int* cur, int NB, int (*sc)[1024]) {
    int t = threadIdx.x;
    for (int i = t; i < 1024; i += 256) sc[0][i] = (i < NB) ? cnt[i] : 0;
    __syncthreads();
    int pin = 0;
    for (int off = 1; off < 1024; off <<= 1) {
        for (int i = t; i < 1024; i += 256) {
            int v = sc[pin][i];
            if (i >= off) v += sc[pin][i - off];
            sc[1 - pin][i] = v;
        }
        __syncthreads();
        pin ^= 1;
    }
    for (int i = t; i <= NB; i += 256) {
        int e = (i == 0) ? 0 : sc[pin][i - 1];
        base[i] = e;
        if (i < NB) cur[i] = e;
    }
    __syncthreads();
}

__global__ __launch_bounds__(256) void k_bscan(const int* cnt_c, int* base_c, int* cur_c, int NBc,
                                               const int* cnt_s, int* base_s, int* cur_s, int NBs) {
    __shared__ int sc[2][1024];
    scan_one(cnt_c, base_c, cur_c, NBc, sc);
    scan_one(cnt_s, base_s, cur_s, NBs, sc);
}

// ---- Phase C: bin packed edges into bucket-partitioned streams ---------
// packed edge: (dst & 127) << 24 | src   (src < 2^24)
__global__ __launch_bounds__(256) void k_bin(const int* src, const int* dst, int* bcur,
                                             int* ebuf, int E, int NB, int CHUNK) {
    __shared__ int cnt[NBMAX];
    __shared__ int slot[NBMAX * KSL];    // 782*16*4 = 50 KB
    int t = threadIdx.x;
    for (long long base = (long long)blockIdx.x * CHUNK; base < E;
         base += (long long)gridDim.x * CHUNK) {
        for (int i = t; i < NB; i += 256) cnt[i] = 0;
        __syncthreads();
        int e1 = (int)base + CHUNK;
        if (e1 > E) e1 = E;
        for (int e = (int)base + t; e < e1; e += 256) {
            int d = dst[e];
            int p = ((d & 127) << 24) | src[e];
            int b = d >> 7;
            int sl = atomicAdd(&cnt[b], 1);
            if (sl < KSL) slot[b * KSL + sl] = p;
            else { int gp = atomicAdd(&bcur[b], 1); ebuf[gp] = p; }  // rare overflow
        }
        __syncthreads();
        for (int b = t; b < NB; b += 256) {
            int c = cnt[b];
            if (c > KSL) c = KSL;
            if (c > 0) {
                int gp = atomicAdd(&bcur[b], c);
                for (int k = 0; k < c; k++) ebuf[gp + k] = slot[b * KSL + k];
            }
        }
        __syncthreads();
    }
}

// ---- Phase D: per-bucket deg/start/csr build (one block per bucket) ----
__global__ __launch_bounds__(256) void k_build(const int* bbase, const int* ebuf,
                                               int* deg, int* start, int* csr, int N) {
    __shared__ int lcnt[128], lofs[128], lcur[128];
    int b = blockIdx.x, t = threadIdx.x;
    int e0 = bbase[b], e1 = bbase[b + 1];
    int n0 = b << 7;
    if (t < 128) lcnt[t] = 0;
    __syncthreads();
    for (int e = e0 + t; e < e1; e += 256)
        atomicAdd(&lcnt[((unsigned)ebuf[e]) >> 24], 1);
    __syncthreads();
    if (t < 64) {   // exclusive scan of 128 values, 2 per lane
        int v0 = lcnt[2 * t], v1 = lcnt[2 * t + 1];
        int s = v0 + v1, incl = s;
        for (int off = 1; off < 64; off <<= 1) {
            int u = __shfl_up(incl, off);
            if (t >= off) incl += u;
        }
        int excl = incl - s;
        lofs[2 * t] = excl;
        lofs[2 * t + 1] = excl + v0;
    }
    __syncthreads();
    if (t < 128) {
        int node = n0 + t;
        if (node < N) { deg[node] = lcnt[t]; start[node] = e0 + lofs[t]; }
        lcur[t] = lofs[t];
    }
    __syncthreads();
    for (int e = e0 + t; e < e1; e += 256) {
        unsigned p = (unsigned)ebuf[e];
        int dl = p >> 24;
        int pos = atomicAdd(&lcur[dl], 1);
        csr[e0 + pos] = (int)(p & 0xFFFFFF);   // writes stay in this bucket's window
    }
}

// ---- Layer 0 pre-GEMM: z[i][c] = dinv[i] * sum_k x[i][k]*W0[k][c] ------
__global__ __launch_bounds__(256) void k_gemm0(const float* x, const float* W,
                                               const int* deg, bf16* z, int N) {
    __shared__ float Wsm[7 * 64];
    int t = threadIdx.x;
    int lane = t & 63;
    int ty = t >> 6;
    for (int i = t; i < 7 * 64; i += 256) Wsm[i] = W[i];
    __syncthreads();
    for (int i = blockIdx.x * 4 + ty; i < N; i += gridDim.x * 4) {
        float xv = 0.f;
        if (lane < 7) xv = x[i * 7 + lane];
        float s = 0.f;
        for (int k = 0; k < 7; k++) s += __shfl(xv, k) * Wsm[k * 64 + lane];
        s *= rsqrtf((float)(deg[i] + 1));
        z[(size_t)i * 64 + lane] = __float2bfloat16(s);
    }
}

// ---- Gather: h[i] = (z[i] + sum_src z[src]) * dinv[i] + b; BN stats ----
// 64-index coalesced prefetch + 16 independent row loads in flight.
__global__ __launch_bounds__(256) void k_gather(const bf16* y, const int* csr,
                                                const int* start, const int* deg,
                                                const float* bias, bf16* h,
                                                float* stat, int N) {
    __shared__ float sm[2][4][64];
    int t = threadIdx.x;
    int lane = t & 63;
    int ty = t >> 6;
    float b = bias[lane];
    float sum = 0.f, sq = 0.f;
    for (int i = blockIdx.x * 4 + ty; i < N; i += gridDim.x * 4) {
        int dg = deg[i];
        int s0 = start[i];
        float acc = b2f(y[(size_t)i * 64 + lane]);   // self-loop term
        float acc2 = 0.f;
        int j = 0;
        while (j < dg) {
            int nchunk = dg - j;
            if (nchunk > 64) nchunk = 64;
            int idx = 0;
            if (lane < nchunk) idx = csr[s0 + j + lane];   // one coalesced load
            int k = 0;
            for (; k + 16 <= nchunk; k += 16) {
                int ii[16];
                float a[16];
                #pragma unroll
                for (int u = 0; u < 16; u++) ii[u] = __shfl(idx, k + u);
                #pragma unroll
                for (int u = 0; u < 16; u++) a[u] = b2f(y[(size_t)ii[u] * 64 + lane]);
                float s1 = ((a[0] + a[1]) + (a[2] + a[3])) + ((a[4] + a[5]) + (a[6] + a[7]));
                float s2 = ((a[8] + a[9]) + (a[10] + a[11])) + ((a[12] + a[13]) + (a[14] + a[15]));
                acc += s1;
                acc2 += s2;
            }
            for (; k + 8 <= nchunk; k += 8) {
                int ii[8];
                float a[8];
                #pragma unroll
                for (int u = 0; u < 8; u++) ii[u] = __shfl(idx, k + u);
                #pragma unroll
                for (int u = 0; u < 8; u++) a[u] = b2f(y[(size_t)ii[u] * 64 + lane]);
                acc += ((a[0] + a[1]) + (a[2] + a[3])) + ((a[4] + a[5]) + (a[6] + a[7]));
            }
            for (; k < nchunk; k++) {
                int s = __shfl(idx, k);
                acc2 += b2f(y[(size_t)s * 64 + lane]);
            }
            j += nchunk;
        }
        float v = (acc + acc2) * rsqrtf((float)(dg + 1)) + b;
        h[(size_t)i * 64 + lane] = __float2bfloat16(v);
        sum += v; sq += v * v;
    }
    sm[0][ty][lane] = sum;
    sm[1][ty][lane] = sq;
    __syncthreads();
    if (ty == 0) {
        atomicAdd(&stat[lane],      sm[0][0][lane] + sm[0][1][lane] + sm[0][2][lane] + sm[0][3][lane]);
        atomicAdd(&stat[64 + lane], sm[1][0][lane] + sm[1][1][lane] + sm[1][2][lane] + sm[1][3][lane]);
    }
}

// ---- Layer 1 GEMM, fused BN0(affine)+ReLU on input ---------------------
__global__ __launch_bounds__(256) void k_gemm1(const bf16* h, const float* W,
                                               const float* stat, const float* gam,
                                               const float* bet, const int* deg,
                                               bf16* y, float invN, int N) {
    __shared__ float Wsm[64 * 64];
    __shared__ float AB[128];
    int t = threadIdx.x;
    int lane = t & 63;
    int ty = t >> 6;
    for (int i = t; i < 4096; i += 256) Wsm[i] = W[i];
    if (t < 64) {
        float mean = stat[t] * invN;
        float var = stat[64 + t] * invN - mean * mean;
        float A = gam[t] * rsqrtf(fmaxf(var, 0.f) + EPS_);
        AB[t] = A;
        AB[64 + t] = bet[t] - mean * A;
    }
    __syncthreads();
    float A = AB[lane];
    float B = AB[64 + lane];
    for (int i = blockIdx.x * 4 + ty; i < N; i += gridDim.x * 4) {
        float v = fmaxf(b2f(h[(size_t)i * 64 + lane]) * A + B, 0.f);
        float s = 0.f;
        for (int k = 0; k < 64; k++) s += __shfl(v, k) * Wsm[k * 64 + lane];
        s *= rsqrtf((float)(deg[i] + 1));
        y[(size_t)i * 64 + lane] = __float2bfloat16(s);
    }
}

// ---- Pool: BN1(affine)+ReLU fused, run-length pre-agg (batch sorted) ---
__global__ __launch_bounds__(256) void k_pool(const bf16* h, const float* stat,
                                              const float* gam, const float* bet,
                                              const int* batch, float* pooled,
                                              float* cnt, float invN, int N) {
    int t = threadIdx.x;
    int lane = t & 63;
    float mean = stat[lane] * invN;
    float var = stat[64 + lane] * invN - mean * mean;
    float A = gam[lane] * rsqrtf(fmaxf(var, 0.f) + EPS_);
    float B = bet[lane] - mean * A;
    int w = (blockIdx.x * 256 + t) >> 6;
    int nw = (gridDim.x * 256) >> 6;
    int chunk = (N + nw - 1) / nw;
    int i0 = w * chunk;
    int i1 = i0 + chunk;
    if (i1 > N) i1 = N;
    if (i0 >= N) return;
    int curg = batch[i0];
    float acc = 0.f, c = 0.f;
    for (int i = i0; i < i1; i++) {
        int g = batch[i];
        if (g != curg) {
            atomicAdd(&pooled[(size_t)curg * 64 + lane], acc);
            if (lane == 0) atomicAdd(&cnt[curg], c);
            curg = g; acc = 0.f; c = 0.f;
        }
        acc += fmaxf(b2f(h[(size_t)i * 64 + lane]) * A + B, 0.f);
        c += 1.f;
    }
    atomicAdd(&pooled[(size_t)curg * 64 + lane], acc);
    if (lane == 0) atomicAdd(&cnt[curg], c);
}

// ---- Head --------------------------------------------------------------
__global__ __launch_bounds__(64) void k_head(const float* pooled_c, const float* cnt_c,
                                             const float* pooled_s, const float* cnt_s,
                                             const float* Wf1, const float* bf1_,
                                             const float* Wf2, const float* bf2_,
                                             float* out) {
    __shared__ float W1sm[128 * 64];
    __shared__ float W2sm[128];
    int t = threadIdx.x;  // blockDim = 64
    for (int i = t; i < 128 * 64; i += 64) W1sm[i] = Wf1[i];
    for (int i = t; i < 128; i += 64) W2sm[i] = Wf2[i];
    __syncthreads();
    float bb1 = bf1_[t];
    float b20 = bf2_[0];
    float b21 = bf2_[1];
    for (int g = blockIdx.x; g < G_; g += gridDim.x) {
        float ic = 1.f / fmaxf(cnt_c[g], 1.f);
        float is = 1.f / fmaxf(cnt_s[g], 1.f);
        float hc = pooled_c[(size_t)g * 64 + t] * ic;
        float hs = pooled_s[(size_t)g * 64 + t] * is;
        float s = bb1;
        for (int k = 0; k < 64; k++) s += __shfl(hc, k) * W1sm[k * 64 + t];
        for (int k = 0; k < 64; k++) s += __shfl(hs, k) * W1sm[(64 + k) * 64 + t];
        s = fmaxf(s, 0.f);
        float p0 = s * W2sm[t * 2 + 0];
        float p1 = s * W2sm[t * 2 + 1];
        for (int off = 32; off > 0; off >>= 1) {
            p0 += __shfl_down(p0, off);
            p1 += __shfl_down(p1, off);
        }
        if (t == 0) {
            out[g * 2 + 0] = p0 + b20;
            out[g * 2 + 1] = p1 + b21;
        }
    }
}

extern "C" void kernel_launch(void* const* d_in, const int* in_sizes, int n_in,
                              void* d_out, int out_size, void* d_ws, size_t ws_size,
                              hipStream_t stream) {
    float* out = (float*)d_out;

    if (n_in != 26 || in_sizes[0] != NC_ * 7 || in_sizes[1] != 2 * EC_ ||
        in_sizes[2] != NC_ || in_sizes[3] != NS_ * 7 || in_sizes[4] != 2 * ES_ ||
        in_sizes[5] != NS_ || out_size != G_ * 2) {
        k_fillout<<<(out_size + 255) / 256, 256, 0, stream>>>(out, 7777.0f, out_size);
        return;
    }
    if (ws_size < (size_t)WS_REQUIRED) {
        k_fillout<<<(out_size + 255) / 256, 256, 0, stream>>>(
            out, 1000.0f + (float)(ws_size >> 20), out_size);
        return;
    }

    const float* x_c     = (const float*)d_in[0];
    const int*   ei_c    = (const int*)d_in[1];
    const int*   batch_c = (const int*)d_in[2];
    const float* x_s     = (const float*)d_in[3];
    const int*   ei_s    = (const int*)d_in[4];
    const int*   batch_s = (const int*)d_in[5];
    const float* Wc0  = (const float*)d_in[6];
    const float* bc0  = (const float*)d_in[7];
    const float* gc0  = (const float*)d_in[8];
    const float* bec0 = (const float*)d_in[9];
    const float* Wc1  = (const float*)d_in[10];
    const float* bc1  = (const float*)d_in[11];
    const float* gc1  = (const float*)d_in[12];
    const float* bec1 = (const float*)d_in[13];
    const float* Ws0  = (const float*)d_in[14];
    const float* bs0  = (const float*)d_in[15];
    const float* gs0  = (const float*)d_in[16];
    const float* bes0 = (const float*)d_in[17];
    const float* Ws1  = (const float*)d_in[18];
    const float* bs1  = (const float*)d_in[19];
    const float* gs1  = (const float*)d_in[20];
    const float* bes1 = (const float*)d_in[21];
    const float* Wf1  = (const float*)d_in[22];
    const float* bf1_ = (const float*)d_in[23];
    const float* Wf2  = (const float*)d_in[24];
    const float* bf2_ = (const float*)d_in[25];

    // ---- workspace layout (4-byte words); total 39,748,612 bytes ----
    int* wsw = (int*)d_ws;
    size_t off = 0;
    float* stats_c  = (float*)(wsw + off); off += 256;   // [0..127] L0, [128..255] L1
    float* stats_s  = (float*)(wsw + off); off += 256;
    float* pooled_c = (float*)(wsw + off); off += (size_t)G_ * 64;
    float* pooled_s = (float*)(wsw + off); off += (size_t)G_ * 64;
    float* cnt_c    = (float*)(wsw + off); off += G_;
    float* cnt_s    = (float*)(wsw + off); off += G_;
    int*   bcnt_c   = wsw + off; off += NB_C;
    int*   bcnt_s   = wsw + off; off += NB_S;
    size_t zero_words = off;
    int*   bbase_c  = wsw + off; off += NB_C + 1;
    int*   bcur_c   = wsw + off; off += NB_C;
    int*   bbase_s  = wsw + off; off += NB_S + 1;
    int*   bcur_s   = wsw + off; off += NB_S;
    int*   deg      = wsw + off; off += NC_;          // shared by branches
    int*   start    = wsw + off; off += NC_;
    int*   csr      = wsw + off; off += EC_;
    int*   ebuf     = wsw + off; off += EC_;
    bf16*  ybuf     = (bf16*)(wsw + off); off += (size_t)NC_ * 32;
    bf16*  hbuf     = (bf16*)(wsw + off); off += (size_t)NC_ * 32;

    k_zero<<<512, 256, 0, stream>>>(wsw, (int)zero_words);

    // ---- CSR prep (histograms + scans for both branches) ----
    k_bhist<<<256, 256, 0, stream>>>(ei_c + EC_, bcnt_c, EC_, NB_C);
    k_bhist<<<256, 256, 0, stream>>>(ei_s + ES_, bcnt_s, ES_, NB_S);
    k_bscan<<<1, 256, 0, stream>>>(bcnt_c, bbase_c, bcur_c, NB_C,
                                   bcnt_s, bbase_s, bcur_s, NB_S);

    // ---- chromo branch ----
    k_bin<<<391, 256, 0, stream>>>(ei_c, ei_c + EC_, bcur_c, ebuf, EC_, NB_C, 4096);
    k_build<<<NB_C, 256, 0, stream>>>(bbase_c, ebuf, deg, start, csr, NC_);
    k_gemm0<<<512, 256, 0, stream>>>(x_c, Wc0, deg, ybuf, NC_);
    k_gather<<<2048, 256, 0, stream>>>(ybuf, csr, start, deg, bc0, hbuf, stats_c, NC_);
    k_gemm1<<<2048, 256, 0, stream>>>(hbuf, Wc1, stats_c, gc0, bec0, deg, ybuf, 1.0f / NC_, NC_);
    k_gather<<<2048, 256, 0, stream>>>(ybuf, csr, start, deg, bc1, hbuf, stats_c + 128, NC_);
    k_pool<<<256, 256, 0, stream>>>(hbuf, stats_c + 128, gc1, bec1, batch_c, pooled_c, cnt_c, 1.0f / NC_, NC_);

    // ---- solvent branch (reuses ebuf/csr/deg/start/ybuf/hbuf) ----
    k_bin<<<391, 256, 0, stream>>>(ei_s, ei_s + ES_, bcur_s, ebuf, ES_, NB_S, 2048);
    k_build<<<NB_S, 256, 0, stream>>>(bbase_s, ebuf, deg, start, csr, NS_);
    k_gemm0<<<512, 256, 0, stream>>>(x_s, Ws0, deg, ybuf, NS_);
    k_gather<<<2048, 256, 0, stream>>>(ybuf, csr, start, deg, bs0, hbuf, stats_s, NS_);
    k_gemm1<<<2048, 256, 0, stream>>>(hbuf, Ws1, stats_s, gs0, bes0, deg, ybuf, 1.0f / NS_, NS_);
    k_gather<<<2048, 256, 0, stream>>>(ybuf, csr, start, deg, bs1, hbuf, stats_s + 128, NS_);
    k_pool<<<256, 256, 0, stream>>>(hbuf, stats_s + 128, gs1, bes1, batch_s, pooled_s, cnt_s, 1.0f / NS_, NS_);

    // ---- head ----
    k_head<<<128, 64, 0, stream>>>(pooled_c, cnt_c, pooled_s, cnt_s, Wf1, bf1_, Wf2, bf2_, out);
}

// Round 9
// 644.432 us; speedup vs baseline: 1.3167x; 1.3167x over previous
//
#include <hip/hip_runtime.h>
#include <hip/hip_bf16.h>

typedef __hip_bfloat16 bf16;

#define NC_ 100000
#define EC_ 1600000
#define NS_ 50000
#define ES_ 800000
#define G_  1024
#define EPS_ 1e-5f

#define NB_C 782          // ceil(100000/128)
#define NB_S 391          // ceil(50000/128)
#define NBMAX 782
#define KSL 16            // LDS slots per bucket in k_bin

#define WS_REQUIRED 39748624ull

__device__ __forceinline__ float b2f(bf16 v) { return __bfloat162float(v); }

__device__ __forceinline__ void acc8(float* a, uint4 r) {
    a[0] += __uint_as_float(r.x << 16); a[1] += __uint_as_float(r.x & 0xffff0000u);
    a[2] += __uint_as_float(r.y << 16); a[3] += __uint_as_float(r.y & 0xffff0000u);
    a[4] += __uint_as_float(r.z << 16); a[5] += __uint_as_float(r.z & 0xffff0000u);
    a[6] += __uint_as_float(r.w << 16); a[7] += __uint_as_float(r.w & 0xffff0000u);
}

__global__ void DualGNN_31327491457689_kernel() {}

__global__ __launch_bounds__(256) void k_fillout(float* out, float val, int n) {
    int i = blockIdx.x * 256 + threadIdx.x;
    if (i < n) out[i] = val;
}

__global__ __launch_bounds__(256) void k_zero(int* p, int n) {
    int i = blockIdx.x * 256 + threadIdx.x;
    int stride = gridDim.x * 256;
    while (i < n) { p[i] = 0; i += stride; }
}

// ---- Phase A: bucket histogram (LDS-staged) ----------------------------
__global__ __launch_bounds__(256) void k_bhist(const int* dst, int* bcnt, int E, int NB) {
    __shared__ int h[NBMAX];
    int t = threadIdx.x;
    for (int i = t; i < NB; i += 256) h[i] = 0;
    __syncthreads();
    for (int e = blockIdx.x * 256 + t; e < E; e += gridDim.x * 256)
        atomicAdd(&h[dst[e] >> 7], 1);
    __syncthreads();
    for (int i = t; i < NB; i += 256) {
        int v = h[i];
        if (v) atomicAdd(&bcnt[i], v);
    }
}

// ---- Phase B: scan bucket counts (both branches, one block) ------------
__device__ void scan_one(const int* cnt, int* base, int* cur, int NB, int (*sc)[1024]) {
    int t = threadIdx.x;
    for (int i = t; i < 1024; i += 256) sc[0][i] = (i < NB) ? cnt[i] : 0;
    __syncthreads();
    int pin = 0;
    for (int off = 1; off < 1024; off <<= 1) {
        for (int i = t; i < 1024; i += 256) {
            int v = sc[pin][i];
            if (i >= off) v += sc[pin][i - off];
            sc[1 - pin][i] = v;
        }
        __syncthreads();
        pin ^= 1;
    }
    for (int i = t; i <= NB; i += 256) {
        int e = (i == 0) ? 0 : sc[pin][i - 1];
        base[i] = e;
        if (i < NB) cur[i] = e;
    }
    __syncthreads();
}

__global__ __launch_bounds__(256) void k_bscan(const int* cnt_c, int* base_c, int* cur_c, int NBc,
                                               const int* cnt_s, int* base_s, int* cur_s, int NBs) {
    __shared__ int sc[2][1024];
    scan_one(cnt_c, base_c, cur_c, NBc, sc);
    scan_one(cnt_s, base_s, cur_s, NBs, sc);
}

// ---- Phase C: bin packed edges into bucket-partitioned streams ---------
// packed edge: (dst & 127) << 24 | src   (src < 2^24)
__global__ __launch_bounds__(256) void k_bin(const int* src, const int* dst, int* bcur,
                                             int* ebuf, int E, int NB, int CHUNK) {
    __shared__ int cnt[NBMAX];
    __shared__ int slot[NBMAX * KSL];    // 782*16*4 = 50 KB
    int t = threadIdx.x;
    for (long long base = (long long)blockIdx.x * CHUNK; base < E;
         base += (long long)gridDim.x * CHUNK) {
        for (int i = t; i < NB; i += 256) cnt[i] = 0;
        __syncthreads();
        int e1 = (int)base + CHUNK;
        if (e1 > E) e1 = E;
        for (int e = (int)base + t; e < e1; e += 256) {
            int d = dst[e];
            int p = ((d & 127) << 24) | src[e];
            int b = d >> 7;
            int sl = atomicAdd(&cnt[b], 1);
            if (sl < KSL) slot[b * KSL + sl] = p;
            else { int gp = atomicAdd(&bcur[b], 1); ebuf[gp] = p; }  // rare overflow
        }
        __syncthreads();
        for (int b = t; b < NB; b += 256) {
            int c = cnt[b];
            if (c > KSL) c = KSL;
            if (c > 0) {
                int gp = atomicAdd(&bcur[b], c);
                for (int k = 0; k < c; k++) ebuf[gp + k] = slot[b * KSL + k];
            }
        }
        __syncthreads();
    }
}

// ---- Phase D: per-bucket deg/start/csr build (one block per bucket) ----
__global__ __launch_bounds__(256) void k_build(const int* bbase, const int* ebuf,
                                               int* deg, int* start, int* csr, int N) {
    __shared__ int lcnt[128], lofs[128], lcur[128];
    int b = blockIdx.x, t = threadIdx.x;
    int e0 = bbase[b], e1 = bbase[b + 1];
    int n0 = b << 7;
    if (t < 128) lcnt[t] = 0;
    __syncthreads();
    for (int e = e0 + t; e < e1; e += 256)
        atomicAdd(&lcnt[((unsigned)ebuf[e]) >> 24], 1);
    __syncthreads();
    if (t < 64) {   // exclusive scan of 128 values, 2 per lane
        int v0 = lcnt[2 * t], v1 = lcnt[2 * t + 1];
        int s = v0 + v1, incl = s;
        for (int off = 1; off < 64; off <<= 1) {
            int u = __shfl_up(incl, off);
            if (t >= off) incl += u;
        }
        int excl = incl - s;
        lofs[2 * t] = excl;
        lofs[2 * t + 1] = excl + v0;
    }
    __syncthreads();
    if (t < 128) {
        int node = n0 + t;
        if (node < N) { deg[node] = lcnt[t]; start[node] = e0 + lofs[t]; }
        lcur[t] = lofs[t];
    }
    __syncthreads();
    for (int e = e0 + t; e < e1; e += 256) {
        unsigned p = (unsigned)ebuf[e];
        int dl = p >> 24;
        int pos = atomicAdd(&lcur[dl], 1);
        csr[e0 + pos] = (int)(p & 0xFFFFFF);   // writes stay in this bucket's window
    }
}

// ---- Layer 0 prep: u[i][0..7] = dinv_i * x[i][k] (bf16x8, 16 B/row) ----
__global__ __launch_bounds__(256) void k_prep7(const float* x, const int* deg,
                                               bf16* u, int N) {
    int i = blockIdx.x * 256 + threadIdx.x;
    if (i >= N) return;
    float d = rsqrtf((float)(deg[i] + 1));
    union __align__(16) Pack { bf16 h[8]; uint4 v; } p;
    for (int k = 0; k < 7; k++) p.h[k] = __float2bfloat16(x[i * 7 + k] * d);
    p.h[7] = __float2bfloat16(0.f);
    ((uint4*)u)[i] = p.v;
}

// ---- Layer 0 gather in rank-7 space + fused 7x64 GEMM + bias + stats ---
// h[i][c] = dinv_i * ((u_i + sum_j u_j) . W0)[c] + b[c]
__global__ __launch_bounds__(256) void k_gather7(const bf16* u, const int* csr,
                                                 const int* start, const int* deg,
                                                 const float* W, const float* bias,
                                                 bf16* h, float* stat, int N) {
    __shared__ float Wsm[7 * 64];
    __shared__ float agg[256][9];        // pad to 9: conflict-free phase-A writes
    __shared__ float sm[2][4][64];
    int t = threadIdx.x, lane = t & 63, ty = t >> 6;
    for (int i = t; i < 448; i += 256) Wsm[i] = W[i];
    float b = bias[lane];
    float sum = 0.f, sq = 0.f;
    const uint4* up = (const uint4*)u;
    for (int base = blockIdx.x * 256; base < N; base += gridDim.x * 256) {
        __syncthreads();                 // agg reuse guard (also covers Wsm init)
        int i = base + t;
        float a[8] = {0.f, 0.f, 0.f, 0.f, 0.f, 0.f, 0.f, 0.f};
        if (i < N) {
            int dg = deg[i], s0 = start[i];
            acc8(a, up[i]);              // self-loop term
            int j = 0;
            for (; j + 4 <= dg; j += 4) {
                int i0 = csr[s0 + j], i1 = csr[s0 + j + 1];
                int i2 = csr[s0 + j + 2], i3 = csr[s0 + j + 3];
                uint4 r0 = up[i0], r1 = up[i1], r2 = up[i2], r3 = up[i3];
                acc8(a, r0); acc8(a, r1); acc8(a, r2); acc8(a, r3);
            }
            for (; j < dg; j++) acc8(a, up[csr[s0 + j]]);
            float di = rsqrtf((float)(dg + 1));
            for (int k = 0; k < 7; k++) a[k] *= di;
        }
        #pragma unroll
        for (int k = 0; k < 7; k++) agg[t][k] = a[k];
        __syncthreads();
        int mbase = base + ty * 64;
        for (int mm = 0; mm < 64; mm++) {
            int node = mbase + mm;
            if (node >= N) break;
            const float* ag = agg[ty * 64 + mm];
            float s = b;
            #pragma unroll
            for (int k = 0; k < 7; k++) s += ag[k] * Wsm[k * 64 + lane];
            h[(size_t)node * 64 + lane] = __float2bfloat16(s);
            sum += s; sq += s * s;
        }
    }
    sm[0][ty][lane] = sum;
    sm[1][ty][lane] = sq;
    __syncthreads();
    if (ty == 0) {
        atomicAdd(&stat[lane],      sm[0][0][lane] + sm[0][1][lane] + sm[0][2][lane] + sm[0][3][lane]);
        atomicAdd(&stat[64 + lane], sm[1][0][lane] + sm[1][1][lane] + sm[1][2][lane] + sm[1][3][lane]);
    }
}

// ---- Layer-1 gather: 64-index coalesced prefetch + 8 row loads in flight
__global__ __launch_bounds__(256) void k_gather(const bf16* y, const int* csr,
                                                const int* start, const int* deg,
                                                const float* bias, bf16* h,
                                                float* stat, int N) {
    __shared__ float sm[2][4][64];
    int t = threadIdx.x;
    int lane = t & 63;
    int ty = t >> 6;
    float b = bias[lane];
    float sum = 0.f, sq = 0.f;
    for (int i = blockIdx.x * 4 + ty; i < N; i += gridDim.x * 4) {
        int dg = deg[i];
        int s0 = start[i];
        float acc = b2f(y[(size_t)i * 64 + lane]);   // self-loop term
        int j = 0;
        while (j < dg) {
            int nchunk = dg - j;
            if (nchunk > 64) nchunk = 64;
            int idx = 0;
            if (lane < nchunk) idx = csr[s0 + j + lane];   // one coalesced load
            int k = 0;
            for (; k + 8 <= nchunk; k += 8) {
                int i0 = __shfl(idx, k + 0);
                int i1 = __shfl(idx, k + 1);
                int i2 = __shfl(idx, k + 2);
                int i3 = __shfl(idx, k + 3);
                int i4 = __shfl(idx, k + 4);
                int i5 = __shfl(idx, k + 5);
                int i6 = __shfl(idx, k + 6);
                int i7 = __shfl(idx, k + 7);
                float a0 = b2f(y[(size_t)i0 * 64 + lane]);   // 8 loads in flight
                float a1 = b2f(y[(size_t)i1 * 64 + lane]);
                float a2 = b2f(y[(size_t)i2 * 64 + lane]);
                float a3 = b2f(y[(size_t)i3 * 64 + lane]);
                float a4 = b2f(y[(size_t)i4 * 64 + lane]);
                float a5 = b2f(y[(size_t)i5 * 64 + lane]);
                float a6 = b2f(y[(size_t)i6 * 64 + lane]);
                float a7 = b2f(y[(size_t)i7 * 64 + lane]);
                acc += ((a0 + a1) + (a2 + a3)) + ((a4 + a5) + (a6 + a7));
            }
            for (; k < nchunk; k++) {
                int s = __shfl(idx, k);
                acc += b2f(y[(size_t)s * 64 + lane]);
            }
            j += nchunk;
        }
        float v = acc * rsqrtf((float)(dg + 1)) + b;
        h[(size_t)i * 64 + lane] = __float2bfloat16(v);
        sum += v; sq += v * v;
    }
    sm[0][ty][lane] = sum;
    sm[1][ty][lane] = sq;
    __syncthreads();
    if (ty == 0) {
        atomicAdd(&stat[lane],      sm[0][0][lane] + sm[0][1][lane] + sm[0][2][lane] + sm[0][3][lane]);
        atomicAdd(&stat[64 + lane], sm[1][0][lane] + sm[1][1][lane] + sm[1][2][lane] + sm[1][3][lane]);
    }
}

// ---- Layer 1 GEMM, fused BN0(affine)+ReLU on input ---------------------
__global__ __launch_bounds__(256) void k_gemm1(const bf16* h, const float* W,
                                               const float* stat, const float* gam,
                                               const float* bet, const int* deg,
                                               bf16* y, float invN, int N) {
    __shared__ float Wsm[64 * 64];
    __shared__ float AB[128];
    int t = threadIdx.x;
    int lane = t & 63;
    int ty = t >> 6;
    for (int i = t; i < 4096; i += 256) Wsm[i] = W[i];
    if (t < 64) {
        float mean = stat[t] * invN;
        float var = stat[64 + t] * invN - mean * mean;
        float A = gam[t] * rsqrtf(fmaxf(var, 0.f) + EPS_);
        AB[t] = A;
        AB[64 + t] = bet[t] - mean * A;
    }
    __syncthreads();
    float A = AB[lane];
    float B = AB[64 + lane];
    for (int i = blockIdx.x * 4 + ty; i < N; i += gridDim.x * 4) {
        float v = fmaxf(b2f(h[(size_t)i * 64 + lane]) * A + B, 0.f);
        float s = 0.f;
        for (int k = 0; k < 64; k++) s += __shfl(v, k) * Wsm[k * 64 + lane];
        s *= rsqrtf((float)(deg[i] + 1));
        y[(size_t)i * 64 + lane] = __float2bfloat16(s);
    }
}

// ---- Pool: BN1(affine)+ReLU fused, run-length pre-agg (batch sorted) ---
__global__ __launch_bounds__(256) void k_pool(const bf16* h, const float* stat,
                                              const float* gam, const float* bet,
                                              const int* batch, float* pooled,
                                              float* cnt, float invN, int N) {
    int t = threadIdx.x;
    int lane = t & 63;
    float mean = stat[lane] * invN;
    float var = stat[64 + lane] * invN - mean * mean;
    float A = gam[lane] * rsqrtf(fmaxf(var, 0.f) + EPS_);
    float B = bet[lane] - mean * A;
    int w = (blockIdx.x * 256 + t) >> 6;
    int nw = (gridDim.x * 256) >> 6;
    int chunk = (N + nw - 1) / nw;
    int i0 = w * chunk;
    int i1 = i0 + chunk;
    if (i1 > N) i1 = N;
    if (i0 >= N) return;
    int curg = batch[i0];
    float acc = 0.f, c = 0.f;
    for (int i = i0; i < i1; i++) {
        int g = batch[i];
        if (g != curg) {
            atomicAdd(&pooled[(size_t)curg * 64 + lane], acc);
            if (lane == 0) atomicAdd(&cnt[curg], c);
            curg = g; acc = 0.f; c = 0.f;
        }
        acc += fmaxf(b2f(h[(size_t)i * 64 + lane]) * A + B, 0.f);
        c += 1.f;
    }
    atomicAdd(&pooled[(size_t)curg * 64 + lane], acc);
    if (lane == 0) atomicAdd(&cnt[curg], c);
}

// ---- Head --------------------------------------------------------------
__global__ __launch_bounds__(64) void k_head(const float* pooled_c, const float* cnt_c,
                                             const float* pooled_s, const float* cnt_s,
                                             const float* Wf1, const float* bf1_,
                                             const float* Wf2, const float* bf2_,
                                             float* out) {
    __shared__ float W1sm[128 * 64];
    __shared__ float W2sm[128];
    int t = threadIdx.x;  // blockDim = 64
    for (int i = t; i < 128 * 64; i += 64) W1sm[i] = Wf1[i];
    for (int i = t; i < 128; i += 64) W2sm[i] = Wf2[i];
    __syncthreads();
    float bb1 = bf1_[t];
    float b20 = bf2_[0];
    float b21 = bf2_[1];
    for (int g = blockIdx.x; g < G_; g += gridDim.x) {
        float ic = 1.f / fmaxf(cnt_c[g], 1.f);
        float is = 1.f / fmaxf(cnt_s[g], 1.f);
        float hc = pooled_c[(size_t)g * 64 + t] * ic;
        float hs = pooled_s[(size_t)g * 64 + t] * is;
        float s = bb1;
        for (int k = 0; k < 64; k++) s += __shfl(hc, k) * W1sm[k * 64 + t];
        for (int k = 0; k < 64; k++) s += __shfl(hs, k) * W1sm[(64 + k) * 64 + t];
        s = fmaxf(s, 0.f);
        float p0 = s * W2sm[t * 2 + 0];
        float p1 = s * W2sm[t * 2 + 1];
        for (int off = 32; off > 0; off >>= 1) {
            p0 += __shfl_down(p0, off);
            p1 += __shfl_down(p1, off);
        }
        if (t == 0) {
            out[g * 2 + 0] = p0 + b20;
            out[g * 2 + 1] = p1 + b21;
        }
    }
}

extern "C" void kernel_launch(void* const* d_in, const int* in_sizes, int n_in,
                              void* d_out, int out_size, void* d_ws, size_t ws_size,
                              hipStream_t stream) {
    float* out = (float*)d_out;

    if (n_in != 26 || in_sizes[0] != NC_ * 7 || in_sizes[1] != 2 * EC_ ||
        in_sizes[2] != NC_ || in_sizes[3] != NS_ * 7 || in_sizes[4] != 2 * ES_ ||
        in_sizes[5] != NS_ || out_size != G_ * 2) {
        k_fillout<<<(out_size + 255) / 256, 256, 0, stream>>>(out, 7777.0f, out_size);
        return;
    }
    if (ws_size < (size_t)WS_REQUIRED) {
        k_fillout<<<(out_size + 255) / 256, 256, 0, stream>>>(
            out, 1000.0f + (float)(ws_size >> 20), out_size);
        return;
    }

    const float* x_c     = (const float*)d_in[0];
    const int*   ei_c    = (const int*)d_in[1];
    const int*   batch_c = (const int*)d_in[2];
    const float* x_s     = (const float*)d_in[3];
    const int*   ei_s    = (const int*)d_in[4];
    const int*   batch_s = (const int*)d_in[5];
    const float* Wc0  = (const float*)d_in[6];
    const float* bc0  = (const float*)d_in[7];
    const float* gc0  = (const float*)d_in[8];
    const float* bec0 = (const float*)d_in[9];
    const float* Wc1  = (const float*)d_in[10];
    const float* bc1  = (const float*)d_in[11];
    const float* gc1  = (const float*)d_in[12];
    const float* bec1 = (const float*)d_in[13];
    const float* Ws0  = (const float*)d_in[14];
    const float* bs0  = (const float*)d_in[15];
    const float* gs0  = (const float*)d_in[16];
    const float* bes0 = (const float*)d_in[17];
    const float* Ws1  = (const float*)d_in[18];
    const float* bs1  = (const float*)d_in[19];
    const float* gs1  = (const float*)d_in[20];
    const float* bes1 = (const float*)d_in[21];
    const float* Wf1  = (const float*)d_in[22];
    const float* bf1_ = (const float*)d_in[23];
    const float* Wf2  = (const float*)d_in[24];
    const float* bf2_ = (const float*)d_in[25];

    // ---- workspace layout (4-byte words); total 39,748,624 bytes ----
    int* wsw = (int*)d_ws;
    size_t off = 0;
    float* stats_c  = (float*)(wsw + off); off += 256;   // [0..127] L0, [128..255] L1
    float* stats_s  = (float*)(wsw + off); off += 256;
    float* pooled_c = (float*)(wsw + off); off += (size_t)G_ * 64;
    float* pooled_s = (float*)(wsw + off); off += (size_t)G_ * 64;
    float* cnt_c    = (float*)(wsw + off); off += G_;
    float* cnt_s    = (float*)(wsw + off); off += G_;
    int*   bcnt_c   = wsw + off; off += NB_C;
    int*   bcnt_s   = wsw + off; off += NB_S;
    size_t zero_words = off;
    int*   bbase_c  = wsw + off; off += NB_C + 1;
    int*   bcur_c   = wsw + off; off += NB_C;
    int*   bbase_s  = wsw + off; off += NB_S + 1;
    int*   bcur_s   = wsw + off; off += NB_S;
    int*   deg      = wsw + off; off += NC_;          // shared by branches
    int*   start    = wsw + off; off += NC_;
    int*   csr      = wsw + off; off += EC_;
    int*   ebuf     = wsw + off; off += EC_;
    off = (off + 3) & ~(size_t)3;                     // 16 B align for uint4 loads
    bf16*  ybuf     = (bf16*)(wsw + off); off += (size_t)NC_ * 32;
    bf16*  hbuf     = (bf16*)(wsw + off); off += (size_t)NC_ * 32;
    bf16*  ubuf     = (bf16*)ybuf;   // u (NC*16 B) aliases ybuf; dead before gemm1 writes y

    k_zero<<<512, 256, 0, stream>>>(wsw, (int)zero_words);

    // ---- CSR prep (histograms + scans for both branches) ----
    k_bhist<<<256, 256, 0, stream>>>(ei_c + EC_, bcnt_c, EC_, NB_C);
    k_bhist<<<256, 256, 0, stream>>>(ei_s + ES_, bcnt_s, ES_, NB_S);
    k_bscan<<<1, 256, 0, stream>>>(bcnt_c, bbase_c, bcur_c, NB_C,
                                   bcnt_s, bbase_s, bcur_s, NB_S);

    // ---- chromo branch ----
    k_bin<<<391, 256, 0, stream>>>(ei_c, ei_c + EC_, bcur_c, ebuf, EC_, NB_C, 4096);
    k_build<<<NB_C, 256, 0, stream>>>(bbase_c, ebuf, deg, start, csr, NC_);
    k_prep7<<<(NC_ + 255) / 256, 256, 0, stream>>>(x_c, deg, ubuf, NC_);
    k_gather7<<<512, 256, 0, stream>>>(ubuf, csr, start, deg, Wc0, bc0, hbuf, stats_c, NC_);
    k_gemm1<<<1024, 256, 0, stream>>>(hbuf, Wc1, stats_c, gc0, bec0, deg, ybuf, 1.0f / NC_, NC_);
    k_gather<<<1024, 256, 0, stream>>>(ybuf, csr, start, deg, bc1, hbuf, stats_c + 128, NC_);
    k_pool<<<256, 256, 0, stream>>>(hbuf, stats_c + 128, gc1, bec1, batch_c, pooled_c, cnt_c, 1.0f / NC_, NC_);

    // ---- solvent branch (reuses ebuf/csr/deg/start/ybuf/hbuf) ----
    k_bin<<<391, 256, 0, stream>>>(ei_s, ei_s + ES_, bcur_s, ebuf, ES_, NB_S, 2048);
    k_build<<<NB_S, 256, 0, stream>>>(bbase_s, ebuf, deg, start, csr, NS_);
    k_prep7<<<(NS_ + 255) / 256, 256, 0, stream>>>(x_s, deg, ubuf, NS_);
    k_gather7<<<256, 256, 0, stream>>>(ubuf, csr, start, deg, Ws0, bs0, hbuf, stats_s, NS_);
    k_gemm1<<<1024, 256, 0, stream>>>(hbuf, Ws1, stats_s, gs0, bes0, deg, ybuf, 1.0f / NS_, NS_);
    k_gather<<<1024, 256, 0, stream>>>(ybuf, csr, start, deg, bs1, hbuf, stats_s + 128, NS_);
    k_pool<<<256, 256, 0, stream>>>(hbuf, stats_s + 128, gs1, bes1, batch_s, pooled_s, cnt_s, 1.0f / NS_, NS_);

    // ---- head ----
    k_head<<<128, 64, 0, stream>>>(pooled_c, cnt_c, pooled_s, cnt_s, Wf1, bf1_, Wf2, bf2_, out);
}